// Round 12
// baseline (107.002 us; speedup 1.0000x reference)
//
#include <hip/hip_runtime.h>

#define NN 4096
#define DD 128
#define MMR 2048
#define KKE 1024
#define FJS 32
#define FCOLS (NN / FJS)      // 128
#define FTILES (FCOLS / 16)   // 8

typedef __attribute__((ext_vector_type(8))) short s16x8;
typedef __attribute__((ext_vector_type(4))) float f32x4;
typedef unsigned short u16;
typedef unsigned int u32;

// ln(1e-45) in fp32
#define SMALLV (-103.61632918439092f)
// exp(2*v - 4) == exp2(v*K1 + K2)
#define K1EXP 2.8853900817779268f
#define K2EXP (-5.7707801635558537f)

static __device__ __forceinline__ u16 f2bf(float x) {
    u32 u = __float_as_uint(x);
    u32 r = (u + 0x7fffu + ((u >> 16) & 1u)) >> 16;
    return (u16)r;
}

static __device__ __forceinline__ f32x4 mfma_bf16(s16x8 a, s16x8 b, f32x4 c) {
    return __builtin_amdgcn_mfma_f32_16x16x32_bf16(a, b, c, 0, 0, 0);
}

static __device__ __forceinline__ void gload_lds16(const void* g, void* l) {
    __builtin_amdgcn_global_load_lds(
        (const __attribute__((address_space(1))) void*)g,
        (__attribute__((address_space(3))) void*)l, 16, 0, 0);
}

// ---------------- prep: zi/z swizzled bf16; real/pseudo/pseudos linear ----------------
// zi/z outputs written in XOR-swizzled chunk order: element d of row r lands
// at u16 index r*128 + (((d>>3)^(r&7))<<3) + (d&7) -> bank-conflict-reduced
// LDS tile reads after linear global_load_lds fill.
__global__ __launch_bounds__(256) void prep_all(
    const float* __restrict__ zi, const float* __restrict__ z,
    const float* __restrict__ real, const float* __restrict__ pseudo,
    const float* __restrict__ pseudos,
    u16* __restrict__ zin_bf, u16* __restrict__ zn_bf,
    u16* __restrict__ real_bf, u16* __restrict__ pseudo_bf,
    u16* __restrict__ pseudos_bf,
    float* __restrict__ nreal, float* __restrict__ npseudo,
    float* __restrict__ npseudos)
{
    int b = blockIdx.x;
    int sub = threadIdx.x >> 6, lane = threadIdx.x & 63;
    if (b < 2048) {
        int row = b * 4 + sub;   // 0..8191
        const float* src = (row < NN) ? zi : z;
        u16* dst = (row < NN) ? zin_bf : zn_bf;
        int r = (row < NN) ? row : row - NN;
        const float* p = src + (size_t)r * DD;
        float a = p[lane], c = p[lane + 64];
        float ss = a * a + c * c;
        #pragma unroll
        for (int d = 1; d < 64; d <<= 1) ss += __shfl_xor(ss, d);
        float nrm = fmaxf(sqrtf(ss), 1e-8f);
        int c0 = lane >> 3, b0 = lane & 7, rs = r & 7;
        dst[r * DD + ((c0 ^ rs) << 3) + b0]       = f2bf(a / nrm);
        dst[r * DD + (((8 + c0) ^ rs) << 3) + b0] = f2bf(c / nrm);
    } else {
        const float* src; u16* dst; float* sq; int r;
        if (b < 3072)      { r = (b - 2048) * 4 + sub; src = real;    dst = real_bf;    sq = nreal; }
        else if (b < 3584) { r = (b - 3072) * 4 + sub; src = pseudo;  dst = pseudo_bf;  sq = npseudo; }
        else               { r = (b - 3584) * 4 + sub; src = pseudos; dst = pseudos_bf; sq = npseudos; }
        const float* p = src + (size_t)r * DD;
        float a = p[lane], c = p[lane + 64];
        float ss = a * a + c * c;
        #pragma unroll
        for (int d = 1; d < 64; d <<= 1) ss += __shfl_xor(ss, d);
        if (lane == 0) sq[r] = ss;
        dst[r * DD + lane]      = f2bf(a);
        dst[r * DD + lane + 64] = f2bf(c);
    }
}

// ---------------- fused main: blocks [0,2048) = feat; [2048,3136) = RBF ----------------
__global__ __launch_bounds__(256) void fused_kernel(
    const u16* __restrict__ zin, const u16* __restrict__ zn,
    const float* __restrict__ y_pse, const float* __restrict__ negw,
    const int* __restrict__ w,
    const u16* __restrict__ real_bf, const u16* __restrict__ pseudo_bf,
    const u16* __restrict__ pseudos_bf,
    const float* __restrict__ nreal, const float* __restrict__ npseudo,
    const float* __restrict__ npseudos,
    float* __restrict__ row_s, float* __restrict__ pos_part,
    float* __restrict__ partials)
{
    __shared__ char lds_t[2][8192];
    __shared__ float lds_red[4];
    int wid = threadIdx.x >> 6;
    int lane = threadIdx.x & 63;
    int lr = lane & 15, lg = lane >> 4;

    if (blockIdx.x < 2048) {
        // ================= feat body =================
        int js = blockIdx.x % FJS;
        int rb = blockIdx.x / FJS;
        int sw = lr & 7;
        int row0 = rb * 64 + wid * 16;
        const char* zin_c = (const char*)zin;
        const char* zn_c  = (const char*)zn;

        int R = row0 + lr;
        s16x8 bfrag[4];
        #pragma unroll
        for (int kk = 0; kk < 4; ++kk)
            bfrag[kk] = *(const s16x8*)(zin_c + (size_t)R * 256 + (((kk * 4 + lg) ^ sw) << 4));

        int j0base = js * FCOLS;
        {
            const char* sA = zn_c  + (size_t)j0base * 256 + wid * 1024 + lane * 16;
            const char* sB = zin_c + (size_t)j0base * 256 + wid * 1024 + lane * 16;
            gload_lds16(sA, &lds_t[0][wid * 1024]);
            gload_lds16(sB, &lds_t[0][4096 + wid * 1024]);
        }
        asm volatile("" ::: "memory");

        const float4* yp  = (const float4*)(y_pse + (size_t)R * NN);
        const float4* npw = (const float4*)(negw  + (size_t)R * NN);
        const int4*   wp  = (const int4*)(w       + (size_t)R * NN);
        int qbase = (j0base >> 2) + lg;
        float4 y_cur = yp[qbase],  y_mid = yp[qbase + 4];
        float4 n_cur = npw[qbase], n_mid = npw[qbase + 4];
        int4   w_cur = wp[qbase],  w_mid = wp[qbase + 4];

        float s0 = 0.0f, pos = 0.0f;

        #pragma unroll
        for (int t = 0; t < FTILES; ++t) {
            if (t + 1 < FTILES) {
                int j1 = j0base + (t + 1) * 16;
                const char* sA = zn_c  + (size_t)j1 * 256 + wid * 1024 + lane * 16;
                const char* sB = zin_c + (size_t)j1 * 256 + wid * 1024 + lane * 16;
                gload_lds16(sA, &lds_t[(t + 1) & 1][wid * 1024]);
                gload_lds16(sB, &lds_t[(t + 1) & 1][4096 + wid * 1024]);
                // FIFO: [m(t)x3, s(t)x2 | m(t+1)x3, s(t+1)x2] -> drain oldest 5
                asm volatile("s_waitcnt vmcnt(5)" ::: "memory");
            } else {
                asm volatile("s_waitcnt vmcnt(0)" ::: "memory");
            }
            __builtin_amdgcn_s_barrier();

            const char* bp = &lds_t[t & 1][0];
            f32x4 accc = {0.f, 0.f, 0.f, 0.f}, acci = {0.f, 0.f, 0.f, 0.f};
            #pragma unroll
            for (int kk = 0; kk < 4; ++kk) {
                int off = lr * 256 + (((kk * 4 + lg) ^ sw) << 4);
                s16x8 an = *(const s16x8*)(bp + off);
                s16x8 ai = *(const s16x8*)(bp + 4096 + off);
                accc = mfma_bf16(an, bfrag[kk], accc);   // C[J,R] = z[J]·zi[R]
                acci = mfma_bf16(ai, bfrag[kk], acci);   // C[J,R] = zi[J]·zi[R]
            }
            int j0 = j0base + t * 16;
            float ya[4] = {y_cur.x, y_cur.y, y_cur.z, y_cur.w};
            float na[4] = {n_cur.x, n_cur.y, n_cur.z, n_cur.w};
            int   wa[4] = {w_cur.x, w_cur.y, w_cur.z, w_cur.w};
            #pragma unroll
            for (int r = 0; r < 4; ++r) {
                int J = j0 + lg * 4 + r;
                float y = ya[r];
                bool wm = (wa[r] != 0) || (R == J);
                float cross = accc[r] * 2.0f;   // cos / TEMP
                float inter = acci[r] * 2.0f;
                if (wm && (y > 0.0f)) pos += y * cross;
                bool nm = (!wm) && (y == 0.0f);
                float nwc = fmaxf(na[r], 0.0f);
                float vc = nm ? nwc * cross : 0.0f;
                vc = (vc == 0.0f) ? SMALLV : vc;
                float vi = nm ? nwc * inter : 0.0f;
                vi = (vi == 0.0f) ? SMALLV : vi;
                s0 += exp2f(fmaf(vc, K1EXP, K2EXP)) + exp2f(fmaf(vi, K1EXP, K2EXP));
            }
            float4 y_new = {0, 0, 0, 0}, n_new = {0, 0, 0, 0};
            int4 w_new = {0, 0, 0, 0};
            if (t + 2 < FTILES) {
                int q = qbase + (t + 2) * 4;
                y_new = yp[q]; n_new = npw[q]; w_new = wp[q];
            }
            y_cur = y_mid; y_mid = y_new;
            n_cur = n_mid; n_mid = n_new;
            w_cur = w_mid; w_mid = w_new;
            asm volatile("s_waitcnt lgkmcnt(0)" ::: "memory");
            __builtin_amdgcn_s_barrier();
        }

        #pragma unroll
        for (int d = 16; d < 64; d <<= 1) s0 += __shfl_xor(s0, d);
        if (lg == 0) row_s[(size_t)R * FJS + js] = s0;
        #pragma unroll
        for (int d = 1; d < 64; d <<= 1) pos += __shfl_xor(pos, d);
        if (lane == 0) lds_red[wid] = pos;
        __syncthreads();
        if (threadIdx.x == 0)
            pos_part[blockIdx.x] = lds_red[0] + lds_red[1] + lds_red[2] + lds_red[3];
    } else {
        // ================= RBF body =================
        int b = blockIdx.x - 2048;
        const u16 *X, *Y; const float *nx, *ny;
        int js, cols, same, local;
        if (b < 512)       { X = real_bf;    Y = real_bf;    nx = nreal;    ny = nreal;    js = 16; cols = 256; same = 1; local = b; }
        else if (b < 768)  { X = pseudo_bf;  Y = pseudo_bf;  nx = npseudo;  ny = npseudo;  js = 16; cols = 128; same = 1; local = b - 512; }
        else if (b < 1024) { X = real_bf;    Y = pseudo_bf;  nx = nreal;    ny = npseudo;  js = 8;  cols = 256; same = 0; local = b - 768; }
        else               { X = pseudos_bf; Y = pseudos_bf; nx = npseudos; ny = npseudos; js = 8;  cols = 128; same = 1; local = b - 1024; }
        int jsx = local % js;
        int rb  = local / js;
        int row0 = rb * 128 + wid * 32;
        const short* Xs = (const short*)X;
        const short* Ys = (const short*)Y;
        s16x8 a0[4], a1[4];
        #pragma unroll
        for (int kk = 0; kk < 4; ++kk) {
            a0[kk] = *(const s16x8*)(Xs + (size_t)(row0 + lr) * DD + kk * 32 + lg * 8);
            a1[kk] = *(const s16x8*)(Xs + (size_t)(row0 + 16 + lr) * DD + kk * 32 + lg * 8);
        }
        float nx0[4], nx1[4];
        #pragma unroll
        for (int r = 0; r < 4; ++r) {
            nx0[r] = nx[row0 + lg * 4 + r];
            nx1[r] = nx[row0 + 16 + lg * 4 + r];
        }
        float sum = 0.0f;
        int j0base = jsx * cols;
        for (int j0 = j0base; j0 < j0base + cols; j0 += 16) {
            int brow = j0 + lr;
            f32x4 c0 = {0.f, 0.f, 0.f, 0.f}, c1 = {0.f, 0.f, 0.f, 0.f};
            #pragma unroll
            for (int kk = 0; kk < 4; ++kk) {
                s16x8 bb = *(const s16x8*)(Ys + (size_t)brow * DD + kk * 32 + lg * 8);
                c0 = mfma_bf16(a0[kk], bb, c0);
                c1 = mfma_bf16(a1[kk], bb, c1);
            }
            int J = j0 + lr;
            float nyJ = ny[J];
            #pragma unroll
            for (int r = 0; r < 4; ++r) {
                int R0 = row0 + lg * 4 + r;
                float d0 = fmaxf(nx0[r] + nyJ - 2.0f * c0[r], 0.0f);
                if (!(same && (R0 == J))) sum += __expf(-d0 * 0.125f);
                int R1 = R0 + 16;
                float d1 = fmaxf(nx1[r] + nyJ - 2.0f * c1[r], 0.0f);
                if (!(same && (R1 == J))) sum += __expf(-d1 * 0.125f);
            }
        }
        #pragma unroll
        for (int d = 1; d < 64; d <<= 1) sum += __shfl_xor(sum, d);
        if (lane == 0) lds_red[wid] = sum;
        __syncthreads();
        if (threadIdx.x == 0)
            partials[b] = lds_red[0] + lds_red[1] + lds_red[2] + lds_red[3];
    }
}

// ---------------- final: LSE + all reductions in ONE single-block kernel ----------------
__global__ __launch_bounds__(256) void final_all(
    const float* __restrict__ row_s, const float* __restrict__ pos_part,
    const float* __restrict__ partials, float* __restrict__ out)
{
    int t = threadIdx.x;
    // per-row LSE: each thread handles 16 rows (R = t + 256*i)
    float lse = 0.0f;
    #pragma unroll
    for (int i = 0; i < 16; ++i) {
        int R = t + 256 * i;
        const float4* rp = (const float4*)(row_s + (size_t)R * FJS);
        float s = 0.0f;
        #pragma unroll
        for (int k = 0; k < FJS / 4; ++k) {
            float4 v = rp[k];
            s += v.x + v.y + v.z + v.w;
        }
        lse += 4.0f + __logf(s);   // fixed-max LSE: max = 4
    }
    float pos = 0.0f;
    #pragma unroll
    for (int i = 0; i < 8; ++i) pos += pos_part[t + 256 * i];
    float xx = partials[t] + partials[t + 256];
    float yy = partials[512 + t];
    float xy = partials[768 + t];
    float pp = (t < 64) ? partials[1024 + t] : 0.0f;
    __shared__ float red[256];
    float vals[6] = {lse, pos, xx, yy, xy, pp};
    float tot[6];
    #pragma unroll
    for (int v = 0; v < 6; ++v) {
        red[t] = vals[v];
        __syncthreads();
        for (int d = 128; d > 0; d >>= 1) {
            if (t < d) red[t] += red[t + d];
            __syncthreads();
        }
        tot[v] = red[0];
        __syncthreads();
    }
    if (t == 0) {
        float feat = (tot[0] - tot[1]) / (float)NN;
        float sxx = tot[2] / ((float)NN * (NN - 1));
        float syy = tot[3] / ((float)MMR * (MMR - 1));
        float sxy = 2.0f * tot[4] / ((float)NN * MMR);
        out[0] = feat + sxx + syy - sxy + tot[5];
    }
}

extern "C" void kernel_launch(void* const* d_in, const int* in_sizes, int n_in,
                              void* d_out, int out_size, void* d_ws, size_t ws_size,
                              hipStream_t stream) {
    const float* zi      = (const float*)d_in[0];
    const float* z       = (const float*)d_in[1];
    const float* y_pse   = (const float*)d_in[2];
    const float* negw    = (const float*)d_in[3];
    const float* real    = (const float*)d_in[4];
    const float* pseudo  = (const float*)d_in[5];
    const float* pseudos = (const float*)d_in[6];
    const int*   w       = (const int*)d_in[7];
    float* out = (float*)d_out;

    char* ws = (char*)d_ws;
    u16* zin_bf     = (u16*)(ws + 0);                     // 1 MB (swizzled)
    u16* zn_bf      = (u16*)(ws + (1 << 20));             // 1 MB (swizzled)
    u16* real_bf    = (u16*)(ws + (2 << 20));             // 1 MB
    u16* pseudo_bf  = (u16*)(ws + (3 << 20));             // 512 KB
    u16* pseudos_bf = (u16*)(ws + (3 << 20) + (1 << 19)); // 256 KB
    float* nreal    = (float*)(ws + (15 << 18));          // 16 KB region
    float* npseudo  = nreal + NN;
    float* npseudos = npseudo + MMR;
    float* row_s    = (float*)(ws + (4 << 20));           // 4096*32 f = 512 KB
    float* pos_part = (float*)(ws + (4 << 20) + (1 << 19)); // 2048 f
    float* partials = pos_part + 2048;                      // 1088 f

    prep_all<<<3840, 256, 0, stream>>>(zi, z, real, pseudo, pseudos,
        zin_bf, zn_bf, real_bf, pseudo_bf, pseudos_bf, nreal, npseudo, npseudos);

    fused_kernel<<<2048 + 1088, 256, 0, stream>>>(
        zin_bf, zn_bf, y_pse, negw, w,
        real_bf, pseudo_bf, pseudos_bf, nreal, npseudo, npseudos,
        row_s, pos_part, partials);

    final_all<<<1, 256, 0, stream>>>(row_s, pos_part, partials, out);
}

// Round 13
// 94.372 us; speedup vs baseline: 1.1338x; 1.1338x over previous
//
#include <hip/hip_runtime.h>

#define NN 4096
#define DD 128
#define MMR 2048
#define KKE 1024
#define FJS 32
#define FCOLS (NN / FJS)      // 128
#define FTILES (FCOLS / 16)   // 8

typedef __attribute__((ext_vector_type(8))) short s16x8;
typedef __attribute__((ext_vector_type(4))) float f32x4;
typedef unsigned short u16;
typedef unsigned int u32;

// ln(1e-45) in fp32
#define SMALLV (-103.61632918439092f)
// exp(2*v - 4) == exp2(v*K1 + K2)
#define K1EXP 2.8853900817779268f
#define K2EXP (-5.7707801635558537f)

static __device__ __forceinline__ u16 f2bf(float x) {
    u32 u = __float_as_uint(x);
    u32 r = (u + 0x7fffu + ((u >> 16) & 1u)) >> 16;
    return (u16)r;
}

static __device__ __forceinline__ f32x4 mfma_bf16(s16x8 a, s16x8 b, f32x4 c) {
    return __builtin_amdgcn_mfma_f32_16x16x32_bf16(a, b, c, 0, 0, 0);
}

static __device__ __forceinline__ void gload_lds16(const void* g, void* l) {
    __builtin_amdgcn_global_load_lds(
        (const __attribute__((address_space(1))) void*)g,
        (__attribute__((address_space(3))) void*)l, 16, 0, 0);
}

// ---------------- prep: zi/z swizzled bf16; real/pseudo/pseudos linear ----------------
// zi/z outputs written in XOR-swizzled chunk order: element d of row r lands
// at u16 index r*128 + (((d>>3)^(r&7))<<3) + (d&7) -> bank-conflict-reduced
// LDS tile reads after linear global_load_lds fill.
__global__ __launch_bounds__(256) void prep_all(
    const float* __restrict__ zi, const float* __restrict__ z,
    const float* __restrict__ real, const float* __restrict__ pseudo,
    const float* __restrict__ pseudos,
    u16* __restrict__ zin_bf, u16* __restrict__ zn_bf,
    u16* __restrict__ real_bf, u16* __restrict__ pseudo_bf,
    u16* __restrict__ pseudos_bf,
    float* __restrict__ nreal, float* __restrict__ npseudo,
    float* __restrict__ npseudos)
{
    int b = blockIdx.x;
    int sub = threadIdx.x >> 6, lane = threadIdx.x & 63;
    if (b < 2048) {
        int row = b * 4 + sub;   // 0..8191
        const float* src = (row < NN) ? zi : z;
        u16* dst = (row < NN) ? zin_bf : zn_bf;
        int r = (row < NN) ? row : row - NN;
        const float* p = src + (size_t)r * DD;
        float a = p[lane], c = p[lane + 64];
        float ss = a * a + c * c;
        #pragma unroll
        for (int d = 1; d < 64; d <<= 1) ss += __shfl_xor(ss, d);
        float nrm = fmaxf(sqrtf(ss), 1e-8f);
        int c0 = lane >> 3, b0 = lane & 7, rs = r & 7;
        dst[r * DD + ((c0 ^ rs) << 3) + b0]       = f2bf(a / nrm);
        dst[r * DD + (((8 + c0) ^ rs) << 3) + b0] = f2bf(c / nrm);
    } else {
        const float* src; u16* dst; float* sq; int r;
        if (b < 3072)      { r = (b - 2048) * 4 + sub; src = real;    dst = real_bf;    sq = nreal; }
        else if (b < 3584) { r = (b - 3072) * 4 + sub; src = pseudo;  dst = pseudo_bf;  sq = npseudo; }
        else               { r = (b - 3584) * 4 + sub; src = pseudos; dst = pseudos_bf; sq = npseudos; }
        const float* p = src + (size_t)r * DD;
        float a = p[lane], c = p[lane + 64];
        float ss = a * a + c * c;
        #pragma unroll
        for (int d = 1; d < 64; d <<= 1) ss += __shfl_xor(ss, d);
        if (lane == 0) sq[r] = ss;
        dst[r * DD + lane]      = f2bf(a);
        dst[r * DD + lane + 64] = f2bf(c);
    }
}

// ---------------- fused main: blocks [0,2048) = feat; [2048,3136) = RBF ----------------
__global__ __launch_bounds__(256) void fused_kernel(
    const u16* __restrict__ zin, const u16* __restrict__ zn,
    const float* __restrict__ y_pse, const float* __restrict__ negw,
    const int* __restrict__ w,
    const u16* __restrict__ real_bf, const u16* __restrict__ pseudo_bf,
    const u16* __restrict__ pseudos_bf,
    const float* __restrict__ nreal, const float* __restrict__ npseudo,
    const float* __restrict__ npseudos,
    float* __restrict__ row_s, float* __restrict__ pos_part,
    float* __restrict__ partials)
{
    __shared__ char lds_t[2][8192];
    __shared__ float lds_red[4];
    int wid = threadIdx.x >> 6;
    int lane = threadIdx.x & 63;
    int lr = lane & 15, lg = lane >> 4;

    if (blockIdx.x < 2048) {
        // ================= feat body =================
        int js = blockIdx.x % FJS;
        int rb = blockIdx.x / FJS;
        int sw = lr & 7;
        int row0 = rb * 64 + wid * 16;
        const char* zin_c = (const char*)zin;
        const char* zn_c  = (const char*)zn;

        int R = row0 + lr;
        s16x8 bfrag[4];
        #pragma unroll
        for (int kk = 0; kk < 4; ++kk)
            bfrag[kk] = *(const s16x8*)(zin_c + (size_t)R * 256 + (((kk * 4 + lg) ^ sw) << 4));

        int j0base = js * FCOLS;
        {
            const char* sA = zn_c  + (size_t)j0base * 256 + wid * 1024 + lane * 16;
            const char* sB = zin_c + (size_t)j0base * 256 + wid * 1024 + lane * 16;
            gload_lds16(sA, &lds_t[0][wid * 1024]);
            gload_lds16(sB, &lds_t[0][4096 + wid * 1024]);
        }
        asm volatile("" ::: "memory");

        const float4* yp  = (const float4*)(y_pse + (size_t)R * NN);
        const float4* npw = (const float4*)(negw  + (size_t)R * NN);
        const int4*   wp  = (const int4*)(w       + (size_t)R * NN);
        int qbase = (j0base >> 2) + lg;
        float4 y_cur = yp[qbase],  y_mid = yp[qbase + 4];
        float4 n_cur = npw[qbase], n_mid = npw[qbase + 4];
        int4   w_cur = wp[qbase],  w_mid = wp[qbase + 4];

        float s0 = 0.0f, pos = 0.0f;

        #pragma unroll
        for (int t = 0; t < FTILES; ++t) {
            if (t + 1 < FTILES) {
                int j1 = j0base + (t + 1) * 16;
                const char* sA = zn_c  + (size_t)j1 * 256 + wid * 1024 + lane * 16;
                const char* sB = zin_c + (size_t)j1 * 256 + wid * 1024 + lane * 16;
                gload_lds16(sA, &lds_t[(t + 1) & 1][wid * 1024]);
                gload_lds16(sB, &lds_t[(t + 1) & 1][4096 + wid * 1024]);
                // FIFO: [m(t)x3, s(t)x2 | m(t+1)x3, s(t+1)x2] -> drain oldest 5
                asm volatile("s_waitcnt vmcnt(5)" ::: "memory");
            } else {
                asm volatile("s_waitcnt vmcnt(0)" ::: "memory");
            }
            __builtin_amdgcn_s_barrier();

            const char* bp = &lds_t[t & 1][0];
            f32x4 accc = {0.f, 0.f, 0.f, 0.f}, acci = {0.f, 0.f, 0.f, 0.f};
            #pragma unroll
            for (int kk = 0; kk < 4; ++kk) {
                int off = lr * 256 + (((kk * 4 + lg) ^ sw) << 4);
                s16x8 an = *(const s16x8*)(bp + off);
                s16x8 ai = *(const s16x8*)(bp + 4096 + off);
                accc = mfma_bf16(an, bfrag[kk], accc);   // C[J,R] = z[J]·zi[R]
                acci = mfma_bf16(ai, bfrag[kk], acci);   // C[J,R] = zi[J]·zi[R]
            }
            int j0 = j0base + t * 16;
            float ya[4] = {y_cur.x, y_cur.y, y_cur.z, y_cur.w};
            float na[4] = {n_cur.x, n_cur.y, n_cur.z, n_cur.w};
            int   wa[4] = {w_cur.x, w_cur.y, w_cur.z, w_cur.w};
            #pragma unroll
            for (int r = 0; r < 4; ++r) {
                int J = j0 + lg * 4 + r;
                float y = ya[r];
                bool wm = (wa[r] != 0) || (R == J);
                float cross = accc[r] * 2.0f;   // cos / TEMP
                float inter = acci[r] * 2.0f;
                if (wm && (y > 0.0f)) pos += y * cross;
                bool nm = (!wm) && (y == 0.0f);
                float nwc = fmaxf(na[r], 0.0f);
                float vc = nm ? nwc * cross : 0.0f;
                vc = (vc == 0.0f) ? SMALLV : vc;
                float vi = nm ? nwc * inter : 0.0f;
                vi = (vi == 0.0f) ? SMALLV : vi;
                s0 += exp2f(fmaf(vc, K1EXP, K2EXP)) + exp2f(fmaf(vi, K1EXP, K2EXP));
            }
            float4 y_new = {0, 0, 0, 0}, n_new = {0, 0, 0, 0};
            int4 w_new = {0, 0, 0, 0};
            if (t + 2 < FTILES) {
                int q = qbase + (t + 2) * 4;
                y_new = yp[q]; n_new = npw[q]; w_new = wp[q];
            }
            y_cur = y_mid; y_mid = y_new;
            n_cur = n_mid; n_mid = n_new;
            w_cur = w_mid; w_mid = w_new;
            asm volatile("s_waitcnt lgkmcnt(0)" ::: "memory");
            __builtin_amdgcn_s_barrier();
        }

        #pragma unroll
        for (int d = 16; d < 64; d <<= 1) s0 += __shfl_xor(s0, d);
        if (lg == 0) row_s[(size_t)R * FJS + js] = s0;
        #pragma unroll
        for (int d = 1; d < 64; d <<= 1) pos += __shfl_xor(pos, d);
        if (lane == 0) lds_red[wid] = pos;
        __syncthreads();
        if (threadIdx.x == 0)
            pos_part[blockIdx.x] = lds_red[0] + lds_red[1] + lds_red[2] + lds_red[3];
    } else {
        // ================= RBF body =================
        int b = blockIdx.x - 2048;
        const u16 *X, *Y; const float *nx, *ny;
        int js, cols, same, local;
        if (b < 512)       { X = real_bf;    Y = real_bf;    nx = nreal;    ny = nreal;    js = 16; cols = 256; same = 1; local = b; }
        else if (b < 768)  { X = pseudo_bf;  Y = pseudo_bf;  nx = npseudo;  ny = npseudo;  js = 16; cols = 128; same = 1; local = b - 512; }
        else if (b < 1024) { X = real_bf;    Y = pseudo_bf;  nx = nreal;    ny = npseudo;  js = 8;  cols = 256; same = 0; local = b - 768; }
        else               { X = pseudos_bf; Y = pseudos_bf; nx = npseudos; ny = npseudos; js = 8;  cols = 128; same = 1; local = b - 1024; }
        int jsx = local % js;
        int rb  = local / js;
        int row0 = rb * 128 + wid * 32;
        const short* Xs = (const short*)X;
        const short* Ys = (const short*)Y;
        s16x8 a0[4], a1[4];
        #pragma unroll
        for (int kk = 0; kk < 4; ++kk) {
            a0[kk] = *(const s16x8*)(Xs + (size_t)(row0 + lr) * DD + kk * 32 + lg * 8);
            a1[kk] = *(const s16x8*)(Xs + (size_t)(row0 + 16 + lr) * DD + kk * 32 + lg * 8);
        }
        float nx0[4], nx1[4];
        #pragma unroll
        for (int r = 0; r < 4; ++r) {
            nx0[r] = nx[row0 + lg * 4 + r];
            nx1[r] = nx[row0 + 16 + lg * 4 + r];
        }
        float sum = 0.0f;
        int j0base = jsx * cols;
        for (int j0 = j0base; j0 < j0base + cols; j0 += 16) {
            int brow = j0 + lr;
            f32x4 c0 = {0.f, 0.f, 0.f, 0.f}, c1 = {0.f, 0.f, 0.f, 0.f};
            #pragma unroll
            for (int kk = 0; kk < 4; ++kk) {
                s16x8 bb = *(const s16x8*)(Ys + (size_t)brow * DD + kk * 32 + lg * 8);
                c0 = mfma_bf16(a0[kk], bb, c0);
                c1 = mfma_bf16(a1[kk], bb, c1);
            }
            int J = j0 + lr;
            float nyJ = ny[J];
            #pragma unroll
            for (int r = 0; r < 4; ++r) {
                int R0 = row0 + lg * 4 + r;
                float d0 = fmaxf(nx0[r] + nyJ - 2.0f * c0[r], 0.0f);
                if (!(same && (R0 == J))) sum += __expf(-d0 * 0.125f);
                int R1 = R0 + 16;
                float d1 = fmaxf(nx1[r] + nyJ - 2.0f * c1[r], 0.0f);
                if (!(same && (R1 == J))) sum += __expf(-d1 * 0.125f);
            }
        }
        #pragma unroll
        for (int d = 1; d < 64; d <<= 1) sum += __shfl_xor(sum, d);
        if (lane == 0) lds_red[wid] = sum;
        __syncthreads();
        if (threadIdx.x == 0)
            partials[b] = lds_red[0] + lds_red[1] + lds_red[2] + lds_red[3];
    }
}

// ---------------- per-row LSE finish (16 blocks — parallel row_s read) ----------------
__global__ __launch_bounds__(256) void lse_part_kernel(
    const float* __restrict__ row_s, float* __restrict__ lse_part)
{
    int R = blockIdx.x * 256 + threadIdx.x;
    float s = 0.0f;
    #pragma unroll
    for (int k = 0; k < FJS; ++k) s += row_s[(size_t)R * FJS + k];
    float v = 4.0f + __logf(s);   // fixed-max LSE: max = 4
    #pragma unroll
    for (int d = 1; d < 64; d <<= 1) v += __shfl_xor(v, d);
    __shared__ float l[4];
    if ((threadIdx.x & 63) == 0) l[threadIdx.x >> 6] = v;
    __syncthreads();
    if (threadIdx.x == 0) lse_part[blockIdx.x] = l[0] + l[1] + l[2] + l[3];
}

// ---------------- final (1 block, deterministic) ----------------
__global__ __launch_bounds__(256) void final_kernel(
    const float* __restrict__ lse_part, const float* __restrict__ pos_part,
    const float* __restrict__ partials, float* __restrict__ out)
{
    int t = threadIdx.x;
    float lse = (t < 16) ? lse_part[t] : 0.0f;
    float pos = 0.0f;
    #pragma unroll
    for (int i = 0; i < 8; ++i) pos += pos_part[t + 256 * i];
    float xx = partials[t] + partials[t + 256];
    float yy = partials[512 + t];
    float xy = partials[768 + t];
    float pp = (t < 64) ? partials[1024 + t] : 0.0f;
    __shared__ float red[256];
    float vals[6] = {lse, pos, xx, yy, xy, pp};
    float tot[6];
    #pragma unroll
    for (int v = 0; v < 6; ++v) {
        red[t] = vals[v];
        __syncthreads();
        for (int d = 128; d > 0; d >>= 1) {
            if (t < d) red[t] += red[t + d];
            __syncthreads();
        }
        tot[v] = red[0];
        __syncthreads();
    }
    if (t == 0) {
        float feat = (tot[0] - tot[1]) / (float)NN;
        float sxx = tot[2] / ((float)NN * (NN - 1));
        float syy = tot[3] / ((float)MMR * (MMR - 1));
        float sxy = 2.0f * tot[4] / ((float)NN * MMR);
        out[0] = feat + sxx + syy - sxy + tot[5];
    }
}

extern "C" void kernel_launch(void* const* d_in, const int* in_sizes, int n_in,
                              void* d_out, int out_size, void* d_ws, size_t ws_size,
                              hipStream_t stream) {
    const float* zi      = (const float*)d_in[0];
    const float* z       = (const float*)d_in[1];
    const float* y_pse   = (const float*)d_in[2];
    const float* negw    = (const float*)d_in[3];
    const float* real    = (const float*)d_in[4];
    const float* pseudo  = (const float*)d_in[5];
    const float* pseudos = (const float*)d_in[6];
    const int*   w       = (const int*)d_in[7];
    float* out = (float*)d_out;

    char* ws = (char*)d_ws;
    u16* zin_bf     = (u16*)(ws + 0);                     // 1 MB (swizzled)
    u16* zn_bf      = (u16*)(ws + (1 << 20));             // 1 MB (swizzled)
    u16* real_bf    = (u16*)(ws + (2 << 20));             // 1 MB
    u16* pseudo_bf  = (u16*)(ws + (3 << 20));             // 512 KB
    u16* pseudos_bf = (u16*)(ws + (3 << 20) + (1 << 19)); // 256 KB
    float* nreal    = (float*)(ws + (15 << 18));          // 16 KB region
    float* npseudo  = nreal + NN;
    float* npseudos = npseudo + MMR;
    float* row_s    = (float*)(ws + (4 << 20));           // 4096*32 f = 512 KB
    float* pos_part = (float*)(ws + (4 << 20) + (1 << 19)); // 2048 f
    float* partials = pos_part + 2048;                      // 1088 f
    float* lse_pv   = partials + 1088;                      // 16 f

    prep_all<<<3840, 256, 0, stream>>>(zi, z, real, pseudo, pseudos,
        zin_bf, zn_bf, real_bf, pseudo_bf, pseudos_bf, nreal, npseudo, npseudos);

    fused_kernel<<<2048 + 1088, 256, 0, stream>>>(
        zin_bf, zn_bf, y_pse, negw, w,
        real_bf, pseudo_bf, pseudos_bf, nreal, npseudo, npseudos,
        row_s, pos_part, partials);

    lse_part_kernel<<<16, 256, 0, stream>>>(row_s, lse_pv);

    final_kernel<<<1, 256, 0, stream>>>(lse_pv, pos_part, partials, out);
}